// Round 3
// baseline (829.411 us; speedup 1.0000x reference)
//
#include <hip/hip_runtime.h>

#define NN 50000
#define EE 800000
#define FIN 256
#define FH 128
#define FC 64
#define LPA_ITERS 10

// edge_index may arrive as int64 (reference dtype) or int32 (harness cast).
// Detection: as int32 words, int64 little-endian layout has every odd word == 0
// (values < 50000). Random int32 indices at odd positions can't all be zero.
__device__ __forceinline__ int edge_at(const int* __restrict__ ei, int is32, int which, int e) {
    int idx = which * EE + e;
    return is32 ? ei[idx] : ei[2 * idx];
}

__global__ void detect_k(const unsigned int* __restrict__ w, int* __restrict__ flag) {
    int any = 0;
    for (int i = 1 + 2 * (int)threadIdx.x; i < 2048; i += 2 * (int)blockDim.x)
        if (w[i] != 0u) any = 1;
    if (any) atomicOr(flag, 1);
}

// One int atomic per edge; returned slot saved (plain coalesced store) so the
// scatter pass needs no atomics at all.
__global__ __launch_bounds__(256) void accum_k(const int* __restrict__ ei,
                                               const int* __restrict__ flag,
                                               int* __restrict__ cnt,
                                               int* __restrict__ slot) {
    int e = blockIdx.x * 256 + threadIdx.x;
    if (e >= EE) return;
    int is32 = *flag;
    int r = edge_at(ei, is32, 0, e);
    slot[e] = atomicAdd(&cnt[r], 1);
}

// CSR row starts via atomic offset allocation + degree histogram for the sort.
__global__ __launch_bounds__(256) void offsets_k(const int* __restrict__ cnt,
                                                 int* __restrict__ start,
                                                 int* __restrict__ gc,
                                                 int* __restrict__ bbase) {
    int i = blockIdx.x * 256 + threadIdx.x;
    if (i >= NN) return;
    int c = cnt[i];
    start[i] = atomicAdd(gc, c);
    atomicAdd(&bbase[c < 63 ? c : 63], 1);
}

// Exclusive scan of the 64 degree buckets (one wave).
__global__ void scan_k(int* __restrict__ b) {
    int l = threadIdx.x;
    int v = b[l];
    int s = v;
    for (int d = 1; d < 64; d <<= 1) {
        int t = __shfl_up(s, d, 64);
        if (l >= d) s += t;
    }
    b[l] = s - v;  // exclusive base; doubles as fill cursor below
}

// perm[] = row ids in ascending-degree order (bucket order; order within a
// bucket is arbitrary and does not affect results).
__global__ __launch_bounds__(256) void permsc_k(const int* __restrict__ cnt,
                                                int* __restrict__ bbase,
                                                int* __restrict__ perm) {
    int i = blockIdx.x * 256 + threadIdx.x;
    if (i >= NN) return;
    int b = cnt[i] < 63 ? cnt[i] : 63;
    perm[atomicAdd(&bbase[b], 1)] = i;
}

// Atomic-free scatter: position = start[row] + slot[edge]. Stores RAW ea;
// row normalization is applied as acc *= deginv[r] inside the spmm.
__global__ __launch_bounds__(256) void scatter_k(const int* __restrict__ ei,
                                                 const int* __restrict__ flag,
                                                 const float* __restrict__ ea,
                                                 const int* __restrict__ start,
                                                 const int* __restrict__ slot,
                                                 uint2* __restrict__ csr) {
    int e = blockIdx.x * 256 + threadIdx.x;
    if (e >= EE) return;
    int is32 = *flag;
    int r = edge_at(ei, is32, 0, e);
    int c = edge_at(ei, is32, 1, e);
    csr[start[r] + slot[e]] = make_uint2((unsigned)c, __float_as_uint(ea[e]));
}

// deg_inv[r] = 1/sum(raw vals of row r) with inf->0; quarter-wave per row.
__global__ __launch_bounds__(256) void rowscale_k(const int* __restrict__ start,
                                                  const int* __restrict__ cnt,
                                                  const uint2* __restrict__ csr,
                                                  float* __restrict__ deginv) {
    int t = threadIdx.x;
    int r = blockIdx.x * 16 + (t >> 4);
    if (r >= NN) return;
    int fl = t & 15;
    int s = start[r], n = cnt[r];
    float sum = 0.f;
    for (int k = fl; k < n; k += 16) sum += __uint_as_float(csr[s + k].y);
    for (int d = 1; d < 16; d <<= 1) sum += __shfl_xor(sum, d, 16);
    if (fl == 0) deginv[r] = sum > 0.f ? 1.f / sum : 0.f;
}

// Simple 64x64 LDS-tiled f32 GEMM (no fp32 MFMA on CDNA4). C = A[M,K] @ B[K,Nn].
__global__ __launch_bounds__(256) void sgemm_k(const float* __restrict__ A,
                                               const float* __restrict__ B,
                                               float* __restrict__ C,
                                               int M, int Nn, int K) {
    __shared__ float As[64 * 17];
    __shared__ float Bs[16 * 64];
    int t = threadIdx.x;
    int bm = blockIdx.x * 64, bn = blockIdx.y * 64;
    int tx = t & 15, ty = t >> 4;
    int arow = t >> 2, akc = (t & 3) * 4;
    int brow = t >> 4, bnc = (t & 15) * 4;
    float acc[4][4] = {};
    for (int k0 = 0; k0 < K; k0 += 16) {
        float4 av = make_float4(0.f, 0.f, 0.f, 0.f);
        int g = bm + arow;
        if (g < M) av = *(const float4*)&A[(size_t)g * K + k0 + akc];
        As[arow * 17 + akc + 0] = av.x;
        As[arow * 17 + akc + 1] = av.y;
        As[arow * 17 + akc + 2] = av.z;
        As[arow * 17 + akc + 3] = av.w;
        float4 bv = *(const float4*)&B[(size_t)(k0 + brow) * Nn + bn + bnc];
        Bs[brow * 64 + bnc + 0] = bv.x;
        Bs[brow * 64 + bnc + 1] = bv.y;
        Bs[brow * 64 + bnc + 2] = bv.z;
        Bs[brow * 64 + bnc + 3] = bv.w;
        __syncthreads();
#pragma unroll
        for (int kk = 0; kk < 16; ++kk) {
            float a[4], b[4];
#pragma unroll
            for (int i = 0; i < 4; ++i) a[i] = As[(ty * 4 + i) * 17 + kk];
#pragma unroll
            for (int j = 0; j < 4; ++j) b[j] = Bs[kk * 64 + tx * 4 + j];
#pragma unroll
            for (int i = 0; i < 4; ++i)
#pragma unroll
                for (int j = 0; j < 4; ++j) acc[i][j] = fmaf(a[i], b[j], acc[i][j]);
        }
        __syncthreads();
    }
#pragma unroll
    for (int i = 0; i < 4; ++i) {
        int g = bm + ty * 4 + i;
        if (g < M) {
            float4 o = make_float4(acc[i][0], acc[i][1], acc[i][2], acc[i][3]);
            *(float4*)&C[(size_t)g * Nn + bn + tx * 4] = o;
        }
    }
}

// SpMM F=64: quarter-wave (16 lanes x float4) per row, rows taken in
// degree-sorted order via perm[] so all groups in a wave have ~equal trip count.
__global__ __launch_bounds__(256) void spmm64_k(const int* __restrict__ perm,
                                                const int* __restrict__ start,
                                                const int* __restrict__ cnt,
                                                const float* __restrict__ deginv,
                                                const uint2* __restrict__ csr,
                                                const float* __restrict__ m,
                                                float* __restrict__ out,
                                                const float* __restrict__ bias,
                                                int relu) {
    int t = threadIdx.x;
    int p = blockIdx.x * 16 + (t >> 4);
    if (p >= NN) return;
    int r = perm[p];
    int fl = t & 15;
    const float4* m4 = (const float4*)m;
    float4 acc = make_float4(0.f, 0.f, 0.f, 0.f);
    int s = start[r], n = cnt[r];
    int k = 0;
    for (; k + 4 <= n; k += 4) {
        uint2 e0 = csr[s + k], e1 = csr[s + k + 1], e2 = csr[s + k + 2], e3 = csr[s + k + 3];
        float4 g0 = m4[(size_t)e0.x * 16 + fl];
        float4 g1 = m4[(size_t)e1.x * 16 + fl];
        float4 g2 = m4[(size_t)e2.x * 16 + fl];
        float4 g3 = m4[(size_t)e3.x * 16 + fl];
        float v0 = __uint_as_float(e0.y), v1 = __uint_as_float(e1.y);
        float v2 = __uint_as_float(e2.y), v3 = __uint_as_float(e3.y);
        acc.x = fmaf(v0, g0.x, acc.x); acc.y = fmaf(v0, g0.y, acc.y);
        acc.z = fmaf(v0, g0.z, acc.z); acc.w = fmaf(v0, g0.w, acc.w);
        acc.x = fmaf(v1, g1.x, acc.x); acc.y = fmaf(v1, g1.y, acc.y);
        acc.z = fmaf(v1, g1.z, acc.z); acc.w = fmaf(v1, g1.w, acc.w);
        acc.x = fmaf(v2, g2.x, acc.x); acc.y = fmaf(v2, g2.y, acc.y);
        acc.z = fmaf(v2, g2.z, acc.z); acc.w = fmaf(v2, g2.w, acc.w);
        acc.x = fmaf(v3, g3.x, acc.x); acc.y = fmaf(v3, g3.y, acc.y);
        acc.z = fmaf(v3, g3.z, acc.z); acc.w = fmaf(v3, g3.w, acc.w);
    }
    for (; k < n; ++k) {
        uint2 e = csr[s + k];
        float v = __uint_as_float(e.y);
        float4 g = m4[(size_t)e.x * 16 + fl];
        acc.x = fmaf(v, g.x, acc.x); acc.y = fmaf(v, g.y, acc.y);
        acc.z = fmaf(v, g.z, acc.z); acc.w = fmaf(v, g.w, acc.w);
    }
    float dv = deginv[r];
    acc.x *= dv; acc.y *= dv; acc.z *= dv; acc.w *= dv;
    if (bias) {
        float4 b = ((const float4*)bias)[fl];
        acc.x += b.x; acc.y += b.y; acc.z += b.z; acc.w += b.w;
    }
    if (relu) {
        acc.x = fmaxf(acc.x, 0.f); acc.y = fmaxf(acc.y, 0.f);
        acc.z = fmaxf(acc.z, 0.f); acc.w = fmaxf(acc.w, 0.f);
    }
    ((float4*)out)[(size_t)r * 16 + fl] = acc;
}

// SpMM F=128: half-wave (32 lanes x float4) per row, degree-sorted.
__global__ __launch_bounds__(256) void spmm128_k(const int* __restrict__ perm,
                                                 const int* __restrict__ start,
                                                 const int* __restrict__ cnt,
                                                 const float* __restrict__ deginv,
                                                 const uint2* __restrict__ csr,
                                                 const float* __restrict__ m,
                                                 float* __restrict__ out,
                                                 const float* __restrict__ bias,
                                                 int relu) {
    int t = threadIdx.x;
    int p = blockIdx.x * 8 + (t >> 5);
    if (p >= NN) return;
    int r = perm[p];
    int fl = t & 31;
    const float4* m4 = (const float4*)m;
    float4 acc = make_float4(0.f, 0.f, 0.f, 0.f);
    int s = start[r], n = cnt[r];
    int k = 0;
    for (; k + 4 <= n; k += 4) {
        uint2 e0 = csr[s + k], e1 = csr[s + k + 1], e2 = csr[s + k + 2], e3 = csr[s + k + 3];
        float4 g0 = m4[(size_t)e0.x * 32 + fl];
        float4 g1 = m4[(size_t)e1.x * 32 + fl];
        float4 g2 = m4[(size_t)e2.x * 32 + fl];
        float4 g3 = m4[(size_t)e3.x * 32 + fl];
        float v0 = __uint_as_float(e0.y), v1 = __uint_as_float(e1.y);
        float v2 = __uint_as_float(e2.y), v3 = __uint_as_float(e3.y);
        acc.x = fmaf(v0, g0.x, acc.x); acc.y = fmaf(v0, g0.y, acc.y);
        acc.z = fmaf(v0, g0.z, acc.z); acc.w = fmaf(v0, g0.w, acc.w);
        acc.x = fmaf(v1, g1.x, acc.x); acc.y = fmaf(v1, g1.y, acc.y);
        acc.z = fmaf(v1, g1.z, acc.z); acc.w = fmaf(v1, g1.w, acc.w);
        acc.x = fmaf(v2, g2.x, acc.x); acc.y = fmaf(v2, g2.y, acc.y);
        acc.z = fmaf(v2, g2.z, acc.z); acc.w = fmaf(v2, g2.w, acc.w);
        acc.x = fmaf(v3, g3.x, acc.x); acc.y = fmaf(v3, g3.y, acc.y);
        acc.z = fmaf(v3, g3.z, acc.z); acc.w = fmaf(v3, g3.w, acc.w);
    }
    for (; k < n; ++k) {
        uint2 e = csr[s + k];
        float v = __uint_as_float(e.y);
        float4 g = m4[(size_t)e.x * 32 + fl];
        acc.x = fmaf(v, g.x, acc.x); acc.y = fmaf(v, g.y, acc.y);
        acc.z = fmaf(v, g.z, acc.z); acc.w = fmaf(v, g.w, acc.w);
    }
    float dv = deginv[r];
    acc.x *= dv; acc.y *= dv; acc.z *= dv; acc.w *= dv;
    if (bias) {
        float4 b = ((const float4*)bias)[fl];
        acc.x += b.x; acc.y += b.y; acc.z += b.z; acc.w += b.w;
    }
    if (relu) {
        acc.x = fmaxf(acc.x, 0.f); acc.y = fmaxf(acc.y, 0.f);
        acc.z = fmaxf(acc.z, 0.f); acc.w = fmaxf(acc.w, 0.f);
    }
    ((float4*)out)[(size_t)r * 32 + fl] = acc;
}

extern "C" void kernel_launch(void* const* d_in, const int* in_sizes, int n_in,
                              void* d_out, int out_size, void* d_ws, size_t ws_size,
                              hipStream_t stream) {
    const float* x    = (const float*)d_in[0];
    const float* soft = (const float*)d_in[1];
    const int*   ei   = (const int*)d_in[2];
    const float* ea   = (const float*)d_in[3];
    const float* W1   = (const float*)d_in[4];
    const float* b1   = (const float*)d_in[5];
    const float* W2   = (const float*)d_in[6];
    const float* b2   = (const float*)d_in[7];
    float* out  = (float*)d_out;                 // [N, C]
    float* labB = out + (size_t)NN * FC;         // [N, C] second output

    char* ws = (char*)d_ws;
    size_t off = 0;
    auto alloc = [&](size_t b) { size_t o = off; off += (b + 255) & ~(size_t)255; return o; };
    size_t o_misc  = alloc(1024);                     // [0]=layout flag, [1]=gcounter, [8..71]=bbase
    size_t o_cnt   = alloc((size_t)NN * 4);
    size_t zero_end = off;
    size_t o_start = alloc((size_t)NN * 4);
    size_t o_perm  = alloc((size_t)NN * 4);
    size_t o_dinv  = alloc((size_t)NN * 4);
    size_t o_slot  = alloc((size_t)EE * 4);
    size_t o_csr   = alloc((size_t)EE * 8);           // packed uint2 {col, raw ea}
    size_t o_t1    = alloc((size_t)NN * FH * 4);      // xW1 -> hW2 -> labA (aliased)
    size_t o_h     = alloc((size_t)NN * FH * 4);
    if (off > ws_size) return;  // insufficient scratch -> visible failure

    int*   misc  = (int*)(ws + o_misc);
    int*   bbase = misc + 8;
    int*   cnt   = (int*)(ws + o_cnt);
    int*   start = (int*)(ws + o_start);
    int*   perm  = (int*)(ws + o_perm);
    float* dinv  = (float*)(ws + o_dinv);
    int*   slot  = (int*)(ws + o_slot);
    uint2* csr   = (uint2*)(ws + o_csr);
    float* t1    = (float*)(ws + o_t1);
    float* h     = (float*)(ws + o_h);
    float* labA  = t1;  // t1 is dead once the second spmm64 has consumed it

    hipMemsetAsync(d_ws, 0, zero_end, stream);
    detect_k<<<1, 256, 0, stream>>>((const unsigned int*)ei, &misc[0]);
    accum_k<<<(EE + 255) / 256, 256, 0, stream>>>(ei, misc, cnt, slot);
    offsets_k<<<(NN + 255) / 256, 256, 0, stream>>>(cnt, start, &misc[1], bbase);
    scan_k<<<1, 64, 0, stream>>>(bbase);
    permsc_k<<<(NN + 255) / 256, 256, 0, stream>>>(cnt, bbase, perm);
    scatter_k<<<(EE + 255) / 256, 256, 0, stream>>>(ei, misc, ea, start, slot, csr);
    rowscale_k<<<(NN + 15) / 16, 256, 0, stream>>>(start, cnt, csr, dinv);

    // h = relu(spmm(x @ W1) + b1)
    sgemm_k<<<dim3((NN + 63) / 64, FH / 64), 256, 0, stream>>>(x, W1, t1, NN, FH, FIN);
    spmm128_k<<<(NN + 7) / 8, 256, 0, stream>>>(perm, start, cnt, dinv, csr, t1, h, b1, 1);

    // out = spmm(h @ W2) + b2
    sgemm_k<<<dim3((NN + 63) / 64, FC / 64), 256, 0, stream>>>(h, W2, t1, NN, FC, FH);
    spmm64_k<<<(NN + 15) / 16, 256, 0, stream>>>(perm, start, cnt, dinv, csr, t1, out, b2, 0);

    // labels: 10 x spmm, ping-pong labA <-> labB; iter 10 (even) lands in labB
    const float* src = soft;
    float* dst = labA;
    for (int it = 0; it < LPA_ITERS; ++it) {
        spmm64_k<<<(NN + 15) / 16, 256, 0, stream>>>(perm, start, cnt, dinv, csr, src, dst, nullptr, 0);
        src = dst;
        dst = (dst == labA) ? labB : labA;
    }
}

// Round 4
// 537.588 us; speedup vs baseline: 1.5428x; 1.5428x over previous
//
#include <hip/hip_runtime.h>

#define NN 50000
#define EE 800000
#define FIN 256
#define FH 128
#define FC 64
#define LPA_ITERS 10
#define NBLK 196  // (NN + 255) / 256

// edge_index may arrive as int64 (reference dtype) or int32 (harness cast).
// Detection: as int32 words, int64 little-endian layout has every odd word == 0
// (values < 50000). Random int32 indices at odd positions can't all be zero.
__device__ __forceinline__ int edge_at(const int* __restrict__ ei, int is32, int which, int e) {
    int idx = which * EE + e;
    return is32 ? ei[idx] : ei[2 * idx];
}

__global__ void detect_k(const unsigned int* __restrict__ w, int* __restrict__ flag) {
    int any = 0;
    for (int i = 1 + 2 * (int)threadIdx.x; i < 2048; i += 2 * (int)blockDim.x)
        if (w[i] != 0u) any = 1;
    if (any) atomicOr(flag, 1);
}

// One int atomic per edge (random 50k addresses, ~16-way mean contention);
// returned slot saved so the scatter pass needs no atomics at all.
__global__ __launch_bounds__(256) void accum_k(const int* __restrict__ ei,
                                               const int* __restrict__ flag,
                                               int* __restrict__ cnt,
                                               int* __restrict__ slot) {
    int e = blockIdx.x * 256 + threadIdx.x;
    if (e >= EE) return;
    int is32 = *flag;
    int r = edge_at(ei, is32, 0, e);
    slot[e] = atomicAdd(&cnt[r], 1);
}

// Block-exclusive scan of cnt + per-block LDS degree histogram.
// Writes: start[i] (partial, block-local exclusive), bsum[blk] (block total),
// blockhist[bucket*NBLK + blk].
__global__ __launch_bounds__(256) void scan1_k(const int* __restrict__ cnt,
                                               int* __restrict__ start,
                                               int* __restrict__ bsum,
                                               int* __restrict__ blockhist) {
    __shared__ int wtot[4];
    __shared__ int hist[64];
    int t = threadIdx.x, blk = blockIdx.x;
    int i = blk * 256 + t;
    if (t < 64) hist[t] = 0;
    __syncthreads();
    int c = (i < NN) ? cnt[i] : 0;
    if (i < NN) atomicAdd(&hist[c < 63 ? c : 63], 1);
    int lane = t & 63, w = t >> 6;
    int s = c;
    for (int d = 1; d < 64; d <<= 1) {
        int u = __shfl_up(s, d, 64);
        if (lane >= d) s += u;
    }
    if (lane == 63) wtot[w] = s;
    __syncthreads();
    int woff = 0;
    for (int j = 0; j < 4; ++j)
        if (j < w) woff += wtot[j];
    int excl = s - c + woff;
    if (i < NN) start[i] = excl;
    if (t == 255) bsum[blk] = excl + c;
    if (t < 64) blockhist[t * NBLK + blk] = hist[t];
}

// Single block: (a) exclusive scan of bsum[0..NBLK), (b) per-bucket running
// scan of blockhist columns + bucket-base exclusive scan folded in.
__global__ void scan2_k(int* __restrict__ bsum, int* __restrict__ blockhist) {
    __shared__ int wtot[4];
    __shared__ int btot[64];
    int t = threadIdx.x;
    int lane = t & 63, w = t >> 6;
    int v = (t < NBLK) ? bsum[t] : 0;
    int s = v;
    for (int d = 1; d < 64; d <<= 1) {
        int u = __shfl_up(s, d, 64);
        if (lane >= d) s += u;
    }
    if (lane == 63) wtot[w] = s;
    __syncthreads();
    int woff = 0;
    for (int j = 0; j < 4; ++j)
        if (j < w) woff += wtot[j];
    if (t < NBLK) bsum[t] = s - v + woff;
    // bucket-major column scan
    if (t < 64) {
        int run = 0;
        for (int j = 0; j < NBLK; ++j) {
            int idx = t * NBLK + j;
            int tmp = blockhist[idx];
            blockhist[idx] = run;
            run += tmp;
        }
        btot[t] = run;
    }
    __syncthreads();
    if (t < 64) {
        int bv = btot[t];
        int bs = bv;
        for (int d = 1; d < 64; d <<= 1) {
            int u = __shfl_up(bs, d, 64);
            if (lane >= d) bs += u;
        }
        int base = bs - bv;
        for (int j = 0; j < NBLK; ++j) blockhist[t * NBLK + j] += base;
    }
}

// Finalize start (add block base) and build perm via LDS-only rank atomics.
// Rank order within (block,bucket) is nondeterministic but only permutes which
// wave processes which row — per-row outputs are unaffected.
__global__ __launch_bounds__(256) void finish_k(const int* __restrict__ cnt,
                                                int* __restrict__ start,
                                                const int* __restrict__ bsum,
                                                const int* __restrict__ blockhist,
                                                int* __restrict__ perm) {
    __shared__ int hist[64];
    int t = threadIdx.x, blk = blockIdx.x;
    int i = blk * 256 + t;
    if (t < 64) hist[t] = 0;
    __syncthreads();
    if (i < NN) {
        start[i] += bsum[blk];
        int c = cnt[i];
        int b = c < 63 ? c : 63;
        int rank = atomicAdd(&hist[b], 1);
        perm[blockhist[b * NBLK + blk] + rank] = i;
    }
}

// Atomic-free scatter: position = start[row] + slot[edge]. Stores RAW ea;
// row normalization is applied as acc *= deginv[r] inside the spmm.
__global__ __launch_bounds__(256) void scatter_k(const int* __restrict__ ei,
                                                 const int* __restrict__ flag,
                                                 const float* __restrict__ ea,
                                                 const int* __restrict__ start,
                                                 const int* __restrict__ slot,
                                                 uint2* __restrict__ csr) {
    int e = blockIdx.x * 256 + threadIdx.x;
    if (e >= EE) return;
    int is32 = *flag;
    int r = edge_at(ei, is32, 0, e);
    int c = edge_at(ei, is32, 1, e);
    csr[start[r] + slot[e]] = make_uint2((unsigned)c, __float_as_uint(ea[e]));
}

// deg_inv[r] = 1/sum(raw vals of row r) with inf->0; quarter-wave per row.
__global__ __launch_bounds__(256) void rowscale_k(const int* __restrict__ start,
                                                  const int* __restrict__ cnt,
                                                  const uint2* __restrict__ csr,
                                                  float* __restrict__ deginv) {
    int t = threadIdx.x;
    int r = blockIdx.x * 16 + (t >> 4);
    if (r >= NN) return;
    int fl = t & 15;
    int s = start[r], n = cnt[r];
    float sum = 0.f;
    for (int k = fl; k < n; k += 16) sum += __uint_as_float(csr[s + k].y);
    for (int d = 1; d < 16; d <<= 1) sum += __shfl_xor(sum, d, 16);
    if (fl == 0) deginv[r] = sum > 0.f ? 1.f / sum : 0.f;
}

// Simple 64x64 LDS-tiled f32 GEMM (no fp32 MFMA on CDNA4). C = A[M,K] @ B[K,Nn].
__global__ __launch_bounds__(256) void sgemm_k(const float* __restrict__ A,
                                               const float* __restrict__ B,
                                               float* __restrict__ C,
                                               int M, int Nn, int K) {
    __shared__ float As[64 * 17];
    __shared__ float Bs[16 * 64];
    int t = threadIdx.x;
    int bm = blockIdx.x * 64, bn = blockIdx.y * 64;
    int tx = t & 15, ty = t >> 4;
    int arow = t >> 2, akc = (t & 3) * 4;
    int brow = t >> 4, bnc = (t & 15) * 4;
    float acc[4][4] = {};
    for (int k0 = 0; k0 < K; k0 += 16) {
        float4 av = make_float4(0.f, 0.f, 0.f, 0.f);
        int g = bm + arow;
        if (g < M) av = *(const float4*)&A[(size_t)g * K + k0 + akc];
        As[arow * 17 + akc + 0] = av.x;
        As[arow * 17 + akc + 1] = av.y;
        As[arow * 17 + akc + 2] = av.z;
        As[arow * 17 + akc + 3] = av.w;
        float4 bv = *(const float4*)&B[(size_t)(k0 + brow) * Nn + bn + bnc];
        Bs[brow * 64 + bnc + 0] = bv.x;
        Bs[brow * 64 + bnc + 1] = bv.y;
        Bs[brow * 64 + bnc + 2] = bv.z;
        Bs[brow * 64 + bnc + 3] = bv.w;
        __syncthreads();
#pragma unroll
        for (int kk = 0; kk < 16; ++kk) {
            float a[4], b[4];
#pragma unroll
            for (int i = 0; i < 4; ++i) a[i] = As[(ty * 4 + i) * 17 + kk];
#pragma unroll
            for (int j = 0; j < 4; ++j) b[j] = Bs[kk * 64 + tx * 4 + j];
#pragma unroll
            for (int i = 0; i < 4; ++i)
#pragma unroll
                for (int j = 0; j < 4; ++j) acc[i][j] = fmaf(a[i], b[j], acc[i][j]);
        }
        __syncthreads();
    }
#pragma unroll
    for (int i = 0; i < 4; ++i) {
        int g = bm + ty * 4 + i;
        if (g < M) {
            float4 o = make_float4(acc[i][0], acc[i][1], acc[i][2], acc[i][3]);
            *(float4*)&C[(size_t)g * Nn + bn + tx * 4] = o;
        }
    }
}

// SpMM F=64: quarter-wave (16 lanes x float4) per row, rows taken in
// degree-sorted order via perm[] so all groups in a wave have ~equal trip count.
__global__ __launch_bounds__(256) void spmm64_k(const int* __restrict__ perm,
                                                const int* __restrict__ start,
                                                const int* __restrict__ cnt,
                                                const float* __restrict__ deginv,
                                                const uint2* __restrict__ csr,
                                                const float* __restrict__ m,
                                                float* __restrict__ out,
                                                const float* __restrict__ bias,
                                                int relu) {
    int t = threadIdx.x;
    int p = blockIdx.x * 16 + (t >> 4);
    if (p >= NN) return;
    int r = perm[p];
    int fl = t & 15;
    const float4* m4 = (const float4*)m;
    float4 acc = make_float4(0.f, 0.f, 0.f, 0.f);
    int s = start[r], n = cnt[r];
    int k = 0;
    for (; k + 4 <= n; k += 4) {
        uint2 e0 = csr[s + k], e1 = csr[s + k + 1], e2 = csr[s + k + 2], e3 = csr[s + k + 3];
        float4 g0 = m4[(size_t)e0.x * 16 + fl];
        float4 g1 = m4[(size_t)e1.x * 16 + fl];
        float4 g2 = m4[(size_t)e2.x * 16 + fl];
        float4 g3 = m4[(size_t)e3.x * 16 + fl];
        float v0 = __uint_as_float(e0.y), v1 = __uint_as_float(e1.y);
        float v2 = __uint_as_float(e2.y), v3 = __uint_as_float(e3.y);
        acc.x = fmaf(v0, g0.x, acc.x); acc.y = fmaf(v0, g0.y, acc.y);
        acc.z = fmaf(v0, g0.z, acc.z); acc.w = fmaf(v0, g0.w, acc.w);
        acc.x = fmaf(v1, g1.x, acc.x); acc.y = fmaf(v1, g1.y, acc.y);
        acc.z = fmaf(v1, g1.z, acc.z); acc.w = fmaf(v1, g1.w, acc.w);
        acc.x = fmaf(v2, g2.x, acc.x); acc.y = fmaf(v2, g2.y, acc.y);
        acc.z = fmaf(v2, g2.z, acc.z); acc.w = fmaf(v2, g2.w, acc.w);
        acc.x = fmaf(v3, g3.x, acc.x); acc.y = fmaf(v3, g3.y, acc.y);
        acc.z = fmaf(v3, g3.z, acc.z); acc.w = fmaf(v3, g3.w, acc.w);
    }
    for (; k < n; ++k) {
        uint2 e = csr[s + k];
        float v = __uint_as_float(e.y);
        float4 g = m4[(size_t)e.x * 16 + fl];
        acc.x = fmaf(v, g.x, acc.x); acc.y = fmaf(v, g.y, acc.y);
        acc.z = fmaf(v, g.z, acc.z); acc.w = fmaf(v, g.w, acc.w);
    }
    float dv = deginv[r];
    acc.x *= dv; acc.y *= dv; acc.z *= dv; acc.w *= dv;
    if (bias) {
        float4 b = ((const float4*)bias)[fl];
        acc.x += b.x; acc.y += b.y; acc.z += b.z; acc.w += b.w;
    }
    if (relu) {
        acc.x = fmaxf(acc.x, 0.f); acc.y = fmaxf(acc.y, 0.f);
        acc.z = fmaxf(acc.z, 0.f); acc.w = fmaxf(acc.w, 0.f);
    }
    ((float4*)out)[(size_t)r * 16 + fl] = acc;
}

// SpMM F=128: half-wave (32 lanes x float4) per row, degree-sorted.
__global__ __launch_bounds__(256) void spmm128_k(const int* __restrict__ perm,
                                                 const int* __restrict__ start,
                                                 const int* __restrict__ cnt,
                                                 const float* __restrict__ deginv,
                                                 const uint2* __restrict__ csr,
                                                 const float* __restrict__ m,
                                                 float* __restrict__ out,
                                                 const float* __restrict__ bias,
                                                 int relu) {
    int t = threadIdx.x;
    int p = blockIdx.x * 8 + (t >> 5);
    if (p >= NN) return;
    int r = perm[p];
    int fl = t & 31;
    const float4* m4 = (const float4*)m;
    float4 acc = make_float4(0.f, 0.f, 0.f, 0.f);
    int s = start[r], n = cnt[r];
    int k = 0;
    for (; k + 4 <= n; k += 4) {
        uint2 e0 = csr[s + k], e1 = csr[s + k + 1], e2 = csr[s + k + 2], e3 = csr[s + k + 3];
        float4 g0 = m4[(size_t)e0.x * 32 + fl];
        float4 g1 = m4[(size_t)e1.x * 32 + fl];
        float4 g2 = m4[(size_t)e2.x * 32 + fl];
        float4 g3 = m4[(size_t)e3.x * 32 + fl];
        float v0 = __uint_as_float(e0.y), v1 = __uint_as_float(e1.y);
        float v2 = __uint_as_float(e2.y), v3 = __uint_as_float(e3.y);
        acc.x = fmaf(v0, g0.x, acc.x); acc.y = fmaf(v0, g0.y, acc.y);
        acc.z = fmaf(v0, g0.z, acc.z); acc.w = fmaf(v0, g0.w, acc.w);
        acc.x = fmaf(v1, g1.x, acc.x); acc.y = fmaf(v1, g1.y, acc.y);
        acc.z = fmaf(v1, g1.z, acc.z); acc.w = fmaf(v1, g1.w, acc.w);
        acc.x = fmaf(v2, g2.x, acc.x); acc.y = fmaf(v2, g2.y, acc.y);
        acc.z = fmaf(v2, g2.z, acc.z); acc.w = fmaf(v2, g2.w, acc.w);
        acc.x = fmaf(v3, g3.x, acc.x); acc.y = fmaf(v3, g3.y, acc.y);
        acc.z = fmaf(v3, g3.z, acc.z); acc.w = fmaf(v3, g3.w, acc.w);
    }
    for (; k < n; ++k) {
        uint2 e = csr[s + k];
        float v = __uint_as_float(e.y);
        float4 g = m4[(size_t)e.x * 32 + fl];
        acc.x = fmaf(v, g.x, acc.x); acc.y = fmaf(v, g.y, acc.y);
        acc.z = fmaf(v, g.z, acc.z); acc.w = fmaf(v, g.w, acc.w);
    }
    float dv = deginv[r];
    acc.x *= dv; acc.y *= dv; acc.z *= dv; acc.w *= dv;
    if (bias) {
        float4 b = ((const float4*)bias)[fl];
        acc.x += b.x; acc.y += b.y; acc.z += b.z; acc.w += b.w;
    }
    if (relu) {
        acc.x = fmaxf(acc.x, 0.f); acc.y = fmaxf(acc.y, 0.f);
        acc.z = fmaxf(acc.z, 0.f); acc.w = fmaxf(acc.w, 0.f);
    }
    ((float4*)out)[(size_t)r * 32 + fl] = acc;
}

extern "C" void kernel_launch(void* const* d_in, const int* in_sizes, int n_in,
                              void* d_out, int out_size, void* d_ws, size_t ws_size,
                              hipStream_t stream) {
    const float* x    = (const float*)d_in[0];
    const float* soft = (const float*)d_in[1];
    const int*   ei   = (const int*)d_in[2];
    const float* ea   = (const float*)d_in[3];
    const float* W1   = (const float*)d_in[4];
    const float* b1   = (const float*)d_in[5];
    const float* W2   = (const float*)d_in[6];
    const float* b2   = (const float*)d_in[7];
    float* out  = (float*)d_out;                 // [N, C]
    float* labB = out + (size_t)NN * FC;         // [N, C] second output

    char* ws = (char*)d_ws;
    size_t off = 0;
    auto alloc = [&](size_t b) { size_t o = off; off += (b + 255) & ~(size_t)255; return o; };
    size_t o_misc  = alloc(256);                      // [0] = layout flag
    size_t o_cnt   = alloc((size_t)NN * 4);
    size_t zero_end = off;
    size_t o_start = alloc((size_t)NN * 4);
    size_t o_perm  = alloc((size_t)NN * 4);
    size_t o_dinv  = alloc((size_t)NN * 4);
    size_t o_bsum  = alloc((size_t)NBLK * 4);
    size_t o_bhist = alloc((size_t)64 * NBLK * 4);
    size_t o_slot  = alloc((size_t)EE * 4);
    size_t o_csr   = alloc((size_t)EE * 8);           // packed uint2 {col, raw ea}
    size_t o_t1    = alloc((size_t)NN * FH * 4);      // xW1 -> hW2 -> labA (aliased)
    size_t o_h     = alloc((size_t)NN * FH * 4);
    if (off > ws_size) return;  // insufficient scratch -> visible failure

    int*   misc  = (int*)(ws + o_misc);
    int*   cnt   = (int*)(ws + o_cnt);
    int*   start = (int*)(ws + o_start);
    int*   perm  = (int*)(ws + o_perm);
    float* dinv  = (float*)(ws + o_dinv);
    int*   bsum  = (int*)(ws + o_bsum);
    int*   bhist = (int*)(ws + o_bhist);
    int*   slot  = (int*)(ws + o_slot);
    uint2* csr   = (uint2*)(ws + o_csr);
    float* t1    = (float*)(ws + o_t1);
    float* h     = (float*)(ws + o_h);
    float* labA  = t1;  // t1 is dead once the second spmm64 has consumed it

    hipMemsetAsync(d_ws, 0, zero_end, stream);
    detect_k<<<1, 256, 0, stream>>>((const unsigned int*)ei, &misc[0]);
    accum_k<<<(EE + 255) / 256, 256, 0, stream>>>(ei, misc, cnt, slot);
    scan1_k<<<NBLK, 256, 0, stream>>>(cnt, start, bsum, bhist);
    scan2_k<<<1, 256, 0, stream>>>(bsum, bhist);
    finish_k<<<NBLK, 256, 0, stream>>>(cnt, start, bsum, bhist, perm);
    scatter_k<<<(EE + 255) / 256, 256, 0, stream>>>(ei, misc, ea, start, slot, csr);
    rowscale_k<<<(NN + 15) / 16, 256, 0, stream>>>(start, cnt, csr, dinv);

    // h = relu(spmm(x @ W1) + b1)
    sgemm_k<<<dim3((NN + 63) / 64, FH / 64), 256, 0, stream>>>(x, W1, t1, NN, FH, FIN);
    spmm128_k<<<(NN + 7) / 8, 256, 0, stream>>>(perm, start, cnt, dinv, csr, t1, h, b1, 1);

    // out = spmm(h @ W2) + b2
    sgemm_k<<<dim3((NN + 63) / 64, FC / 64), 256, 0, stream>>>(h, W2, t1, NN, FC, FH);
    spmm64_k<<<(NN + 15) / 16, 256, 0, stream>>>(perm, start, cnt, dinv, csr, t1, out, b2, 0);

    // labels: 10 x spmm, ping-pong labA <-> labB; iter 10 (even count) lands in labB
    const float* src = soft;
    float* dst = labA;
    for (int it = 0; it < LPA_ITERS; ++it) {
        spmm64_k<<<(NN + 15) / 16, 256, 0, stream>>>(perm, start, cnt, dinv, csr, src, dst, nullptr, 0);
        src = dst;
        dst = (dst == labA) ? labB : labA;
    }
}